// Round 11
// baseline (744.438 us; speedup 1.0000x reference)
//
#include <hip/hip_runtime.h>
#include <hip/hip_bf16.h>

// GraphAE: pseudo == 0 => only W[0] of the 8 spline matrices matters.
// Linearization: mean(h[src])@W2_0 == mean(h[src]@W2_0) -> project before gather.
// Round 20 (= R19 with compile fix: nontemporal builtins need clang
// ext_vector_type, not HIP_vector_type uint4):
//  - Budget: TWO ~46us harness poison fills inside every measured window;
//    controllable kernels in R13 ~= 107us; aggs (54us, LLC-bound) largest.
//  - Third locality attempt, flaws of R15 (line amplification) and R18
//    (blockIdx->XCD mapping assumption + esrc L2 pollution) fixed:
//    (a) half = s_getreg(HW_REG_XCC_ID)&1  -> correct per-XCD table slice
//        under ANY scheduler mapping (perf-only; correctness independent);
//    (b) work via per-half global atomic queues (self-balancing);
//    (c) esrc/offs/outputs use nontemporal load/store -> 3.2MB half-table
//        is the only L2-resident stream per XCD (< 4MB L2).
//  - CSR + prep + split-output GEMM identical to R18 (all proven passing).
//
// Verified MFMA layouts (guide §3): A[m=lane&15][k=(lane>>4)*8+j],
// B[k=(lane>>4)*8+j][n=lane&15], D[row=(lane>>4)*4+r][col=lane&15].

#define THREADS 256

typedef __attribute__((ext_vector_type(8))) short bf16x8;   // 8 bf16 = 4 VGPRs
typedef __attribute__((ext_vector_type(4))) float f32x4;    // acc
typedef __attribute__((ext_vector_type(4))) unsigned int u32x4;  // NT-capable 16B

__device__ __forceinline__ float bf2f(unsigned short u) {
    unsigned v = ((unsigned)u) << 16;
    return __builtin_bit_cast(float, v);
}
__device__ __forceinline__ unsigned short f2bf(float f) {
    __hip_bfloat16 h = __float2bfloat16(f);   // RNE
    return __builtin_bit_cast(unsigned short, h);
}
__device__ __forceinline__ void acc8(float* f, uint4 v) {
    f[0] += bf2f((unsigned short)v.x); f[1] += bf2f((unsigned short)(v.x >> 16));
    f[2] += bf2f((unsigned short)v.y); f[3] += bf2f((unsigned short)(v.y >> 16));
    f[4] += bf2f((unsigned short)v.z); f[5] += bf2f((unsigned short)(v.z >> 16));
    f[6] += bf2f((unsigned short)v.w); f[7] += bf2f((unsigned short)(v.w >> 16));
}
__device__ __forceinline__ void acc8v(float* f, u32x4 v) {
    f[0] += bf2f((unsigned short)v.x); f[1] += bf2f((unsigned short)(v.x >> 16));
    f[2] += bf2f((unsigned short)v.y); f[3] += bf2f((unsigned short)(v.y >> 16));
    f[4] += bf2f((unsigned short)v.z); f[5] += bf2f((unsigned short)(v.z >> 16));
    f[6] += bf2f((unsigned short)v.w); f[7] += bf2f((unsigned short)(v.w >> 16));
}
__device__ __forceinline__ int get_xcc() {
    int v;
    asm volatile("s_getreg_b32 %0, hwreg(HW_REG_XCC_ID)" : "=s"(v));
    return v;
}

// ---------------- weight pack ----------------
// Pack fp32 W (eff. K x NOUT) into MFMA B-frag layout bf16:
// dst[(((s*NB + j)*64 + lane)*8 + i] = W[s*32 + (lane>>4)*8 + i][j*16 + (lane&15)]
__device__ __forceinline__ void pack_one(unsigned short* dst,
                                         const float* W0, const float* W1,
                                         int NB, int ksplit, int colsplit,
                                         int ld0, int ld1, int t) {
    int i = t & 7, lane = (t >> 3) & 63, rest = t >> 9;
    int j = rest % NB, s = rest / NB;
    int k = s * 32 + ((lane >> 4) << 3) + i;
    int c = (j << 4) + (lane & 15);
    float v;
    if (c >= colsplit)    v = W1[(size_t)k * ld1 + (c - colsplit)];
    else if (k >= ksplit) v = W1[(size_t)(k - ksplit) * ld1 + c];
    else                  v = W0[(size_t)k * ld0 + c];
    dst[t] = f2bf(v);
}

#define BIG (1 << 30)

// prep: weight packs + x->bf16 (ab1 cols 64:128 AND split xh) + bucket hist
__global__ void prep_kernel(const float* __restrict__ W1g, const float* __restrict__ root1,
                            const float* __restrict__ W2g, const float* __restrict__ root2,
                            const float* __restrict__ dw1, const float* __restrict__ dw2,
                            const float* __restrict__ x, const int* __restrict__ dstv,
                            int* __restrict__ bcnt,
                            unsigned short* __restrict__ Pb1,   // 128x256
                            unsigned short* __restrict__ Pb2,   // 256x128
                            unsigned short* __restrict__ Pd1,   // 64x256
                            unsigned short* __restrict__ Pd2,   // 256x64
                            unsigned short* __restrict__ ab1,   // N x 128
                            unsigned short* __restrict__ xh,    // [2][np][32]
                            int n, int np, int E, int pb_pack) {
    if ((int)blockIdx.x >= pb_pack) {
        __shared__ int hist[256];
        int t = threadIdx.x;
        hist[t] = 0;
        __syncthreads();
        int e0 = ((int)blockIdx.x - pb_pack) * 4096;
#pragma unroll
        for (int i = 0; i < 16; ++i) {
            int e = e0 + t + i * 256;
            if (e < E) atomicAdd(&hist[dstv[e] >> 8], 1);
        }
        __syncthreads();
        int h = hist[t];
        if (h) atomicAdd(&bcnt[t], h);
        return;
    }
    int t = blockIdx.x * blockDim.x + threadIdx.x;
    if (t < 32768) {
        pack_one(Pb1, W1g, root1, 16, 64, BIG, 256, 256, t);
    } else if (t < 65536) {
        pack_one(Pb2, W2g, root2, 8, BIG, 64, 64, 64, t - 32768);
    } else if (t < 81920) {
        pack_one(Pd1, dw1, dw1, 16, BIG, BIG, 256, 256, t - 65536);
    } else if (t < 98304) {
        pack_one(Pd2, dw2, dw2, 4, BIG, BIG, 64, 64, t - 81920);
    } else if (t < 98304 + n * 16) {
        int u = t - 98304;
        int row = u >> 4, c4 = (u & 15) * 4;
        float4 v = *(const float4*)(x + (size_t)row * 64 + c4);
        unsigned lo = (unsigned)f2bf(v.x) | ((unsigned)f2bf(v.y) << 16);
        unsigned hi = (unsigned)f2bf(v.z) | ((unsigned)f2bf(v.w) << 16);
        uint2 o; o.x = lo; o.y = hi;
        *(uint2*)(ab1 + (size_t)row * 128 + 64 + c4) = o;
        int hh = c4 >> 5, off = c4 & 31;
        *(uint2*)(xh + (size_t)hh * np * 32 + (size_t)row * 32 + off) = o;
    }
}

// Pass A (R13): partition edges into buckets of 256 consecutive dst nodes.
__global__ __launch_bounds__(512) void partition_edges(
    const int* __restrict__ src, const int* __restrict__ dst,
    const int* __restrict__ bcnt, int* __restrict__ bcur,
    int* __restrict__ epack, int E) {
    __shared__ int hist[256];
    __shared__ int base[256];
    __shared__ int lcur[256];
    __shared__ int bb[256];
    int t = threadIdx.x;
    if (t < 256) { hist[t] = 0; lcur[t] = 0; }
    __syncthreads();
    int e0 = blockIdx.x * 2048;
    int myd[4], mys[4];
#pragma unroll
    for (int i = 0; i < 4; ++i) {
        int e = e0 + t + i * 512;
        int d = (e < E) ? dst[e] : -1;
        mys[i] = (e < E) ? src[e] : 0;
        myd[i] = d;
        if (d >= 0) atomicAdd(&hist[d >> 8], 1);
    }
    int cb = 0;
    if (t < 256) { cb = bcnt[t]; bb[t] = cb; }
    __syncthreads();
    for (int off = 1; off < 256; off <<= 1) {
        int xv = (t >= off && t < 256) ? bb[t - off] : 0;
        __syncthreads();
        if (t < 256) bb[t] += xv;
        __syncthreads();
    }
    if (t < 256) {
        int h = hist[t];
        if (h > 0) base[t] = (bb[t] - cb) + atomicAdd(&bcur[t], h);
    }
    __syncthreads();
#pragma unroll
    for (int i = 0; i < 4; ++i) {
        int d = myd[i];
        if (d >= 0) {
            int b = d >> 8;
            int p = atomicAdd(&lcur[b], 1);
            epack[base[b] + p] = ((d & 255) << 20) | mys[i];
        }
    }
}

// Pass B (R13): one block (1024 thr) per 256-node bucket.
__global__ __launch_bounds__(1024) void bucket_fill2(
    const int* __restrict__ epack, const int* __restrict__ bcnt,
    int* __restrict__ offs, float* __restrict__ invd,
    int* __restrict__ esrc, int N) {
    __shared__ int sb_[256];
    __shared__ int nh[256];
    __shared__ int loff[256];
    __shared__ int ncur[256];
    __shared__ int stage[8192];
    int b = blockIdx.x, t = threadIdx.x;
    int n0 = b << 8;
    int cb = 0;
    if (t < 256) { cb = bcnt[t]; sb_[t] = cb; }
    __syncthreads();
    for (int off = 1; off < 256; off <<= 1) {
        int xv = (t >= off && t < 256) ? sb_[t - off] : 0;
        __syncthreads();
        if (t < 256) sb_[t] += xv;
        __syncthreads();
    }
    int ebase = b ? sb_[b - 1] : 0;
    int ecount = sb_[b] - ebase;
    if (b == 0 && t == 0) offs[N] = sb_[255];
    if (t < 256) nh[t] = 0;
    __syncthreads();
    for (int i = t; i < ecount; i += 1024)
        atomicAdd(&nh[epack[ebase + i] >> 20], 1);
    __syncthreads();
    int v = 0;
    if (t < 256) { v = nh[t]; loff[t] = v; }
    __syncthreads();
    for (int off = 1; off < 256; off <<= 1) {
        int xv = (t >= off && t < 256) ? loff[t - off] : 0;
        __syncthreads();
        if (t < 256) loff[t] += xv;
        __syncthreads();
    }
    if (t < 256) {
        int ex = loff[t] - v;
        loff[t] = ex;
        int node = n0 + t;
        if (node < N) {
            offs[node] = ebase + ex;
            invd[node] = 1.0f / (float)max(v, 1);
        }
        ncur[t] = 0;
    }
    __syncthreads();
    bool useLds = (ecount <= 8192);
    for (int i = t; i < ecount; i += 1024) {
        int p = epack[ebase + i];
        int dl = p >> 20;
        int pos = atomicAdd(&ncur[dl], 1);
        int g = loff[dl] + pos;
        int sv = p & 0xFFFFF;
        if (useLds) stage[g] = sv;
        else        esrc[ebase + g] = sv;
    }
    __syncthreads();
    if (useLds)
        for (int i = t; i < ecount; i += 1024) esrc[ebase + i] = stage[i];
}

// ---------------- XCD-keyed L2-resident half gathers ----------------
// half = XCC_ID & 1 (physical, mapping-independent). Each XCD's L2 caches
// only its 3.2MB half-table; esrc/offs/outputs are nontemporal so the
// table is the only resident stream. Work via per-half atomic queue
// (self-balancing regardless of XCD parity distribution of blocks).
// Wave = one (node, half): 16 edge slots x 4 lanes x 16B of the 64B half-row.
// MODE 0: ab1[node][h*32+..] = mean(x[src]) half     (table xh)
// MODE 1: z[node][h*32+..] = mean(hw[src]) + hroot + b2   (table hwh)
template <int MODE>
__global__ __launch_bounds__(256) void agg_q(
    const unsigned short* __restrict__ tbl,      // [2][np][32]
    const int* __restrict__ esrc, const int* __restrict__ offs,
    const float* __restrict__ invd,
    const unsigned short* __restrict__ hrootb,   // [np][64] (MODE 1)
    const float* __restrict__ b2,
    unsigned short* __restrict__ outb, int* __restrict__ qctr,
    int n, int np, int ngroups) {
    __shared__ int sh[2];
    if (threadIdx.x == 0) {
        int half = get_xcc() & 1;
        sh[0] = half;
        sh[1] = atomicAdd(&qctr[half], 1);
    }
    __syncthreads();
    const int h = sh[0], g = sh[1];
    if (g >= ngroups) return;
    const int node = g * 4 + (threadIdx.x >> 6);
    if (node >= n) return;
    const int l = threadIdx.x & 63;
    const int slot = l >> 2, c = l & 3;
    const unsigned short* tb = tbl + (size_t)h * np * 32 + c * 8;
    int s0 = __builtin_nontemporal_load(offs + node);
    int e0 = __builtin_nontemporal_load(offs + node + 1);
    float a[8] = {};
    for (int j = s0 + slot; __any(j < e0); j += 16) {
        if (j < e0) {
            int src = __builtin_nontemporal_load(esrc + j);
            uint4 v = *(const uint4*)(tb + (size_t)src * 32);
            acc8(a, v);
        }
    }
#pragma unroll
    for (int k = 0; k < 8; ++k) {
        a[k] += __shfl_xor(a[k], 4);
        a[k] += __shfl_xor(a[k], 8);
        a[k] += __shfl_xor(a[k], 16);
        a[k] += __shfl_xor(a[k], 32);
    }
    if (slot == 0) {
        float iv = invd[node];
        float v[8];
#pragma unroll
        for (int k = 0; k < 8; ++k) v[k] = a[k] * iv;
        int fo = h * 32 + c * 8;                 // feature offset
        if (MODE == 1) {
            u32x4 hr = __builtin_nontemporal_load(
                (const u32x4*)(hrootb + (size_t)node * 64 + fo));
            float4 bA = *(const float4*)(b2 + fo);
            float4 bB = *(const float4*)(b2 + fo + 4);
            v[0] += bf2f((unsigned short)hr.x)         + bA.x;
            v[1] += bf2f((unsigned short)(hr.x >> 16)) + bA.y;
            v[2] += bf2f((unsigned short)hr.y)         + bA.z;
            v[3] += bf2f((unsigned short)(hr.y >> 16)) + bA.w;
            v[4] += bf2f((unsigned short)hr.z)         + bB.x;
            v[5] += bf2f((unsigned short)(hr.z >> 16)) + bB.y;
            v[6] += bf2f((unsigned short)hr.w)         + bB.z;
            v[7] += bf2f((unsigned short)(hr.w >> 16)) + bB.w;
        }
        u32x4 o;
        o.x = (unsigned)f2bf(v[0]) | ((unsigned)f2bf(v[1]) << 16);
        o.y = (unsigned)f2bf(v[2]) | ((unsigned)f2bf(v[3]) << 16);
        o.z = (unsigned)f2bf(v[4]) | ((unsigned)f2bf(v[5]) << 16);
        o.w = (unsigned)f2bf(v[6]) | ((unsigned)f2bf(v[7]) << 16);
        const int OS = (MODE == 0) ? 128 : 64;
        __builtin_nontemporal_store(o, (u32x4*)(outb + (size_t)node * OS + fo));
    }
}

// ---------------- fused double-GEMM ----------------
// Stage 1: T = relu(A @ Wp1 + bias1)  (A: n x K1 bf16, T: 64 x 256 tile in LDS)
// Stage 2: C = T @ Wp2 (+ bias2)
// OUTM 0: fp32 out, stride 64. OUTM 1: split bf16 -> cols 0:63 into
// Cv=[2][np][32] halves, cols 64:127 into Cv2=[np][64].
template <int K1, int NBW2, int OUTM>
__global__ __launch_bounds__(256) void gemm_fused(
    const unsigned short* __restrict__ A,
    const unsigned short* __restrict__ Bp1, const float* __restrict__ bias1,
    const unsigned short* __restrict__ Bp2, const float* __restrict__ bias2,
    void* __restrict__ Cv, unsigned short* __restrict__ Cv2, int n, int np)
{
    constexpr int KS1 = K1 / 32;
    constexpr int NB2 = NBW2 * 4;
    __shared__ unsigned short ht[64][264];

    const int m0 = blockIdx.x * 64;
    const int lane = threadIdx.x & 63;
    const int w = threadIdx.x >> 6;
    const int quad = lane >> 4;
    const int l16 = lane & 15;

    // ---- stage 1 ----
    {
        f32x4 acc[4][4] = {};
        const unsigned short* Arow = A + (size_t)(m0 + l16) * K1 + quad * 8;
        for (int s = 0; s < KS1; ++s) {
            bf16x8 a[4];
#pragma unroll
            for (int mb = 0; mb < 4; ++mb)
                a[mb] = *(const bf16x8*)(Arow + (size_t)mb * 16 * K1 + s * 32);
#pragma unroll
            for (int jn = 0; jn < 4; ++jn) {
                int j = w * 4 + jn;
                bf16x8 b = *(const bf16x8*)(Bp1 + ((size_t)(s * 16 + j) * 64 + lane) * 8);
#pragma unroll
                for (int mb = 0; mb < 4; ++mb)
                    acc[mb][jn] = __builtin_amdgcn_mfma_f32_16x16x32_bf16(a[mb], b, acc[mb][jn], 0, 0, 0);
            }
        }
#pragma unroll
        for (int jn = 0; jn < 4; ++jn) {
            int col = (w * 4 + jn) * 16 + l16;
            float bv = bias1[col];
#pragma unroll
            for (int mb = 0; mb < 4; ++mb)
#pragma unroll
                for (int r = 0; r < 4; ++r) {
                    int row = mb * 16 + quad * 4 + r;
                    ht[row][col] = f2bf(fmaxf(acc[mb][jn][r] + bv, 0.f));
                }
        }
    }
    __syncthreads();

    // ---- stage 2 ----
    {
        f32x4 acc[4][NBW2] = {};
        for (int s = 0; s < 8; ++s) {
            bf16x8 a[4];
#pragma unroll
            for (int mb = 0; mb < 4; ++mb)
                a[mb] = *(const bf16x8*)&ht[mb * 16 + l16][s * 32 + quad * 8];
#pragma unroll
            for (int jn = 0; jn < NBW2; ++jn) {
                int j = w * NBW2 + jn;
                bf16x8 b = *(const bf16x8*)(Bp2 + ((size_t)(s * NB2 + j) * 64 + lane) * 8);
#pragma unroll
                for (int mb = 0; mb < 4; ++mb)
                    acc[mb][jn] = __builtin_amdgcn_mfma_f32_16x16x32_bf16(a[mb], b, acc[mb][jn], 0, 0, 0);
            }
        }
#pragma unroll
        for (int jn = 0; jn < NBW2; ++jn) {
            int col = (w * NBW2 + jn) * 16 + l16;
            float bv = bias2 ? bias2[col] : 0.f;
#pragma unroll
            for (int mb = 0; mb < 4; ++mb)
#pragma unroll
                for (int r = 0; r < 4; ++r) {
                    int row = m0 + mb * 16 + quad * 4 + r;
                    if (row < n) {
                        float vv = acc[mb][jn][r] + bv;
                        if (OUTM == 1) {
                            unsigned short val = f2bf(vv);
                            if (col < 64)
                                ((unsigned short*)Cv)[(size_t)(col >> 5) * np * 32 +
                                                      (size_t)row * 32 + (col & 31)] = val;
                            else
                                Cv2[(size_t)row * 64 + (col - 64)] = val;
                        } else {
                            ((float*)Cv)[(size_t)row * 64 + col] = vv;
                        }
                    }
                }
        }
    }
}

extern "C" void kernel_launch(void* const* d_in, const int* in_sizes, int n_in,
                              void* d_out, int out_size, void* d_ws, size_t ws_size,
                              hipStream_t stream) {
    const float* x      = (const float*)d_in[0];
    const int*   ei     = (const int*)d_in[1];
    const float* W1g    = (const float*)d_in[2];   // (8,64,256): [0] = first 16384
    const float* root1  = (const float*)d_in[3];
    const float* b1     = (const float*)d_in[4];
    const float* W2g    = (const float*)d_in[5];   // (8,256,64): [0] = first 16384
    const float* root2  = (const float*)d_in[6];
    const float* b2     = (const float*)d_in[7];
    const float* dw1    = (const float*)d_in[8];
    const float* db1    = (const float*)d_in[9];
    const float* dw2    = (const float*)d_in[10];
    const float* db2    = (const float*)d_in[11];
    float* out = (float*)d_out;

    const int N = in_sizes[0] / 64;
    const int E = in_sizes[1] / 2;
    const int Npad = N + 64;
    const int* srcv = ei;
    const int* dstv = ei + E;

    char* ws = (char*)d_ws;
    auto alloc = [&](size_t bytes) -> void* {
        void* p = (void*)ws;
        ws += (bytes + 255) & ~(size_t)255;
        return p;
    };
    int*   bcnt   = (int*)alloc(1024);               // per-bucket counts (256)
    int*   bcur   = (int*)alloc(1024);               // 0-based bucket cursors
    int*   qctr   = (int*)alloc(256);                // agg work queues (4 used)
    int*   offs   = (int*)alloc((size_t)(N + 1) * 4);
    float* invd   = (float*)alloc((size_t)N * 4);
    int*   esrc   = (int*)alloc((size_t)E * 4);
    int*   epack  = (int*)alloc((size_t)E * 4);
    unsigned short* Pb1 = (unsigned short*)alloc(32768 * 2);
    unsigned short* Pb2 = (unsigned short*)alloc(32768 * 2);
    unsigned short* Pd1 = (unsigned short*)alloc(16384 * 2);
    unsigned short* Pd2 = (unsigned short*)alloc(16384 * 2);
    unsigned short* ab1    = (unsigned short*)alloc((size_t)Npad * 128 * 2);  // [agg1 | xb]
    unsigned short* xh     = (unsigned short*)alloc((size_t)2 * Npad * 32 * 2);
    unsigned short* hwh    = (unsigned short*)alloc((size_t)2 * Npad * 32 * 2);
    unsigned short* hrootb = (unsigned short*)alloc((size_t)Npad * 64 * 2);
    unsigned short* z      = (unsigned short*)alloc((size_t)Npad * 64 * 2);

    hipMemsetAsync(bcnt, 0, 2304, stream);           // bcnt + bcur + qctr

    int gb = (N + 63) / 64;
    int nbkt = (N + 255) / 256;
    int pa = (E + 4095) / 4096;                      // prep hist blocks
    int pa2 = (E + 2047) / 2048;                     // partition blocks
    int pb_pack = (98304 + N * 16 + THREADS - 1) / THREADS;
    int ngrp = (N + 3) / 4;                          // agg node groups

    // packs + x->bf16 (ab1 + xh halves) + bucket histogram
    prep_kernel<<<pb_pack + pa, THREADS, 0, stream>>>(
        W1g, root1, W2g, root2, dw1, dw2, x, dstv, bcnt,
        Pb1, Pb2, Pd1, Pd2, ab1, xh, N, Npad, E, pb_pack);
    // bucket-level CSR (R13 forms)
    partition_edges<<<pa2, 512, 0, stream>>>(srcv, dstv, bcnt, bcur, epack, E);
    bucket_fill2<<<nbkt, 1024, 0, stream>>>(epack, bcnt, offs, invd, esrc, N);

    // layer 1: XCD-keyed half agg + fused [L1 GEMM -> split L2 projection]
    agg_q<0><<<ngrp * 2, THREADS, 0, stream>>>(xh, esrc, offs, invd,
                                               nullptr, nullptr, ab1,
                                               qctr, N, Npad, ngrp);
    gemm_fused<128, 2, 1><<<gb, 256, 0, stream>>>(ab1, Pb1, b1, Pb2, nullptr,
                                                  hwh, hrootb, N, Npad);
    // layer 2: XCD-keyed half agg (+root+bias) -> z
    agg_q<1><<<ngrp * 2, THREADS, 0, stream>>>(hwh, esrc, offs, invd,
                                               hrootb, b2, z,
                                               qctr + 2, N, Npad, ngrp);
    // fused decoder [dec1 -> dec2]
    gemm_fused<64, 1, 0><<<gb, 256, 0, stream>>>(z, Pd1, db1, Pd2, db2,
                                                 out, nullptr, N, Npad);
}

// Round 12
// 197.028 us; speedup vs baseline: 3.7783x; 3.7783x over previous
//
#include <hip/hip_runtime.h>
#include <hip/hip_bf16.h>

// GraphAE: pseudo == 0 => only W[0] of the 8 spline matrices matters.
// Linearization: mean(h[src])@W2_0 == mean(h[src]@W2_0) -> project before gather.
// Round 21 = exact revert to R13 (best measured: 199.0us).
// Session budget (closed): ~92us harness poison-fills (in-window, untouchable)
// + ~54us aggs (LLC random-gather floor; 3 locality schemes all regressed)
// + ~25us gemms + ~25us prep/CSR + ~5us gaps.
//
// Verified MFMA layouts (guide §3): A[m=lane&15][k=(lane>>4)*8+j],
// B[k=(lane>>4)*8+j][n=lane&15], D[row=(lane>>4)*4+r][col=lane&15].

#define THREADS 256

typedef __attribute__((ext_vector_type(8))) short bf16x8;   // 8 bf16 = 4 VGPRs
typedef __attribute__((ext_vector_type(4))) float f32x4;    // acc

__device__ __forceinline__ float bf2f(unsigned short u) {
    unsigned v = ((unsigned)u) << 16;
    return __builtin_bit_cast(float, v);
}
__device__ __forceinline__ unsigned short f2bf(float f) {
    __hip_bfloat16 h = __float2bfloat16(f);   // RNE
    return __builtin_bit_cast(unsigned short, h);
}
__device__ __forceinline__ void acc8(float* f, uint4 v) {
    f[0] += bf2f((unsigned short)v.x); f[1] += bf2f((unsigned short)(v.x >> 16));
    f[2] += bf2f((unsigned short)v.y); f[3] += bf2f((unsigned short)(v.y >> 16));
    f[4] += bf2f((unsigned short)v.z); f[5] += bf2f((unsigned short)(v.z >> 16));
    f[6] += bf2f((unsigned short)v.w); f[7] += bf2f((unsigned short)(v.w >> 16));
}

// ---------------- weight pack ----------------
// Pack fp32 W (eff. K x NOUT) into MFMA B-frag layout bf16:
// dst[(((s*NB + j)*64 + lane)*8 + i] = W[s*32 + (lane>>4)*8 + i][j*16 + (lane&15)]
__device__ __forceinline__ void pack_one(unsigned short* dst,
                                         const float* W0, const float* W1,
                                         int NB, int ksplit, int colsplit,
                                         int ld0, int ld1, int t) {
    int i = t & 7, lane = (t >> 3) & 63, rest = t >> 9;
    int j = rest % NB, s = rest / NB;
    int k = s * 32 + ((lane >> 4) << 3) + i;
    int c = (j << 4) + (lane & 15);
    float v;
    if (c >= colsplit)    v = W1[(size_t)k * ld1 + (c - colsplit)];
    else if (k >= ksplit) v = W1[(size_t)(k - ksplit) * ld1 + c];
    else                  v = W0[(size_t)k * ld0 + c];
    dst[t] = f2bf(v);
}

#define BIG (1 << 30)

// prep: weight packs + x->bf16 (vectorized) + bucket histogram (edge blocks)
__global__ void prep_kernel(const float* __restrict__ W1g, const float* __restrict__ root1,
                            const float* __restrict__ W2g, const float* __restrict__ root2,
                            const float* __restrict__ dw1, const float* __restrict__ dw2,
                            const float* __restrict__ x, const int* __restrict__ dstv,
                            int* __restrict__ bcnt,
                            unsigned short* __restrict__ Pb1,   // 128x256
                            unsigned short* __restrict__ Pb2,   // 256x128
                            unsigned short* __restrict__ Pd1,   // 64x256
                            unsigned short* __restrict__ Pd2,   // 256x64
                            unsigned short* __restrict__ ab1,   // N x 128, x -> cols 64:128
                            int n, int E, int pb_pack) {
    if ((int)blockIdx.x >= pb_pack) {
        __shared__ int hist[256];
        int t = threadIdx.x;
        hist[t] = 0;
        __syncthreads();
        int e0 = ((int)blockIdx.x - pb_pack) * 4096;
#pragma unroll
        for (int i = 0; i < 16; ++i) {
            int e = e0 + t + i * 256;
            if (e < E) atomicAdd(&hist[dstv[e] >> 8], 1);
        }
        __syncthreads();
        int h = hist[t];
        if (h) atomicAdd(&bcnt[t], h);
        return;
    }
    int t = blockIdx.x * blockDim.x + threadIdx.x;
    if (t < 32768) {
        pack_one(Pb1, W1g, root1, 16, 64, BIG, 256, 256, t);
    } else if (t < 65536) {
        pack_one(Pb2, W2g, root2, 8, BIG, 64, 64, 64, t - 32768);
    } else if (t < 81920) {
        pack_one(Pd1, dw1, dw1, 16, BIG, BIG, 256, 256, t - 65536);
    } else if (t < 98304) {
        pack_one(Pd2, dw2, dw2, 4, BIG, BIG, 64, 64, t - 81920);
    } else if (t < 98304 + n * 16) {
        int u = t - 98304;
        int row = u >> 4, c4 = (u & 15) * 4;
        float4 v = *(const float4*)(x + (size_t)row * 64 + c4);
        unsigned lo = (unsigned)f2bf(v.x) | ((unsigned)f2bf(v.y) << 16);
        unsigned hi = (unsigned)f2bf(v.z) | ((unsigned)f2bf(v.w) << 16);
        uint2 o; o.x = lo; o.y = hi;
        *(uint2*)(ab1 + (size_t)row * 128 + 64 + c4) = o;
    }
}

// Pass A: partition edges into buckets of 256 consecutive dst nodes.
// 512 threads x 2048 edges/block (391 blocks, 3128 waves) for latency hiding.
__global__ __launch_bounds__(512) void partition_edges(
    const int* __restrict__ src, const int* __restrict__ dst,
    const int* __restrict__ bcnt, int* __restrict__ bcur,
    int* __restrict__ epack, int E) {
    __shared__ int hist[256];
    __shared__ int base[256];
    __shared__ int lcur[256];
    __shared__ int bb[256];
    int t = threadIdx.x;
    if (t < 256) { hist[t] = 0; lcur[t] = 0; }
    __syncthreads();
    int e0 = blockIdx.x * 2048;
    int myd[4], mys[4];
#pragma unroll
    for (int i = 0; i < 4; ++i) {
        int e = e0 + t + i * 512;
        int d = (e < E) ? dst[e] : -1;
        mys[i] = (e < E) ? src[e] : 0;
        myd[i] = d;
        if (d >= 0) atomicAdd(&hist[d >> 8], 1);
    }
    // local exclusive scan of bcnt -> bucket bases (t<256 active)
    int cb = 0;
    if (t < 256) { cb = bcnt[t]; bb[t] = cb; }
    __syncthreads();
    for (int off = 1; off < 256; off <<= 1) {
        int xv = (t >= off && t < 256) ? bb[t - off] : 0;
        __syncthreads();
        if (t < 256) bb[t] += xv;
        __syncthreads();
    }
    if (t < 256) {
        int h = hist[t];
        if (h > 0) base[t] = (bb[t] - cb) + atomicAdd(&bcur[t], h);
    }
    __syncthreads();
#pragma unroll
    for (int i = 0; i < 4; ++i) {
        int d = myd[i];
        if (d >= 0) {
            int b = d >> 8;
            int p = atomicAdd(&lcur[b], 1);
            epack[base[b] + p] = ((d & 255) << 20) | mys[i];
        }
    }
}

// Pass B: one block (1024 threads, 16 waves) per 256-node bucket.
// Local per-node histogram + scan in LDS (emits offs and invd), then
// bucket-local ordering + coalesced esrc write.
__global__ __launch_bounds__(1024) void bucket_fill2(
    const int* __restrict__ epack, const int* __restrict__ bcnt,
    int* __restrict__ offs, float* __restrict__ invd,
    int* __restrict__ esrc, int N) {
    __shared__ int sb_[256];
    __shared__ int nh[256];
    __shared__ int loff[256];
    __shared__ int ncur[256];
    __shared__ int stage[8192];
    int b = blockIdx.x, t = threadIdx.x;
    int n0 = b << 8;
    // bucket base via local scan of bcnt
    int cb = 0;
    if (t < 256) { cb = bcnt[t]; sb_[t] = cb; }
    __syncthreads();
    for (int off = 1; off < 256; off <<= 1) {
        int xv = (t >= off && t < 256) ? sb_[t - off] : 0;
        __syncthreads();
        if (t < 256) sb_[t] += xv;
        __syncthreads();
    }
    int ebase = b ? sb_[b - 1] : 0;
    int ecount = sb_[b] - ebase;
    if (b == 0 && t == 0) offs[N] = sb_[255];
    if (t < 256) nh[t] = 0;
    __syncthreads();
    for (int i = t; i < ecount; i += 1024)
        atomicAdd(&nh[epack[ebase + i] >> 20], 1);
    __syncthreads();
    int v = 0;
    if (t < 256) { v = nh[t]; loff[t] = v; }
    __syncthreads();
    for (int off = 1; off < 256; off <<= 1) {
        int xv = (t >= off && t < 256) ? loff[t - off] : 0;
        __syncthreads();
        if (t < 256) loff[t] += xv;
        __syncthreads();
    }
    if (t < 256) {
        int ex = loff[t] - v;
        loff[t] = ex;
        int node = n0 + t;
        if (node < N) {
            offs[node] = ebase + ex;
            invd[node] = 1.0f / (float)max(v, 1);
        }
        ncur[t] = 0;
    }
    __syncthreads();
    bool useLds = (ecount <= 8192);
    for (int i = t; i < ecount; i += 1024) {
        int p = epack[ebase + i];
        int dl = p >> 20;
        int pos = atomicAdd(&ncur[dl], 1);
        int g = loff[dl] + pos;         // bucket-local slot
        int sv = p & 0xFFFFF;
        if (useLds) stage[g] = sv;
        else        esrc[ebase + g] = sv;
    }
    __syncthreads();
    if (useLds)
        for (int i = t; i < ecount; i += 1024) esrc[ebase + i] = stage[i];
}

// ---------------- gathers: 16B/lane, 8 edges per wave-instr, 16-edge unroll ----
// lane = slot(8) x c(8); lane loads features [c*8, c*8+8) of edge (j+slot).
// agg1 = mean(x[src]): reads ab1 cols 64:128, writes ab1 cols 0:64.
__global__ void agg_x4(unsigned short* __restrict__ ab1, const int* __restrict__ esrc,
                       const int* __restrict__ offs, const float* __restrict__ invd,
                       int n) {
    int node = blockIdx.x * 4 + (threadIdx.x >> 6);
    if (node >= n) return;
    int l = threadIdx.x & 63;
    int slot = l >> 3, c = l & 7;
    const unsigned short* xb = ab1 + 64 + c * 8;
    int s = offs[node], e = offs[node + 1];
    float a0[8] = {}, a1[8] = {};
    int j = s;
    for (; j + 16 <= e; j += 16) {
        int i0 = esrc[j + slot], i1 = esrc[j + 8 + slot];
        uint4 v0 = *(const uint4*)(xb + (size_t)i0 * 128);
        uint4 v1 = *(const uint4*)(xb + (size_t)i1 * 128);
        acc8(a0, v0); acc8(a1, v1);
    }
    if (j + 8 <= e) {
        int i0 = esrc[j + slot];
        uint4 v0 = *(const uint4*)(xb + (size_t)i0 * 128);
        acc8(a0, v0);
        j += 8;
    }
    if (slot < e - j) {
        int i0 = esrc[j + slot];
        uint4 v0 = *(const uint4*)(xb + (size_t)i0 * 128);
        acc8(a1, v0);
    }
    float r[8];
#pragma unroll
    for (int k = 0; k < 8; ++k) {
        r[k] = a0[k] + a1[k];
        r[k] += __shfl_xor(r[k], 8);
        r[k] += __shfl_xor(r[k], 16);
        r[k] += __shfl_xor(r[k], 32);
    }
    if (slot == 0) {
        float iv = invd[node];
        unsigned p0 = (unsigned)f2bf(r[0] * iv) | ((unsigned)f2bf(r[1] * iv) << 16);
        unsigned p1 = (unsigned)f2bf(r[2] * iv) | ((unsigned)f2bf(r[3] * iv) << 16);
        unsigned p2 = (unsigned)f2bf(r[4] * iv) | ((unsigned)f2bf(r[5] * iv) << 16);
        unsigned p3 = (unsigned)f2bf(r[6] * iv) | ((unsigned)f2bf(r[7] * iv) << 16);
        uint4 o; o.x = p0; o.y = p1; o.z = p2; o.w = p3;
        *(uint4*)(ab1 + (size_t)node * 128 + c * 8) = o;
    }
}

// z = mean(hw[src]) + hroot + b2 ; hwroot N x 128 bf16 (0:64 hw, 64:128 hroot)
__global__ void agg_z4(const unsigned short* __restrict__ hwroot,
                       const int* __restrict__ esrc, const int* __restrict__ offs,
                       const float* __restrict__ invd, const float* __restrict__ b2,
                       unsigned short* __restrict__ z, int n) {
    int node = blockIdx.x * 4 + (threadIdx.x >> 6);
    if (node >= n) return;
    int l = threadIdx.x & 63;
    int slot = l >> 3, c = l & 7;
    const unsigned short* hb = hwroot + c * 8;
    int s = offs[node], e = offs[node + 1];
    float a0[8] = {}, a1[8] = {};
    int j = s;
    for (; j + 16 <= e; j += 16) {
        int i0 = esrc[j + slot], i1 = esrc[j + 8 + slot];
        uint4 v0 = *(const uint4*)(hb + (size_t)i0 * 128);
        uint4 v1 = *(const uint4*)(hb + (size_t)i1 * 128);
        acc8(a0, v0); acc8(a1, v1);
    }
    if (j + 8 <= e) {
        int i0 = esrc[j + slot];
        uint4 v0 = *(const uint4*)(hb + (size_t)i0 * 128);
        acc8(a0, v0);
        j += 8;
    }
    if (slot < e - j) {
        int i0 = esrc[j + slot];
        uint4 v0 = *(const uint4*)(hb + (size_t)i0 * 128);
        acc8(a1, v0);
    }
    float r[8];
#pragma unroll
    for (int k = 0; k < 8; ++k) {
        r[k] = a0[k] + a1[k];
        r[k] += __shfl_xor(r[k], 8);
        r[k] += __shfl_xor(r[k], 16);
        r[k] += __shfl_xor(r[k], 32);
    }
    if (slot == 0) {
        float iv = invd[node];
        uint4 hr = *(const uint4*)(hwroot + (size_t)node * 128 + 64 + c * 8);
        float4 bA = *(const float4*)(b2 + c * 8);
        float4 bB = *(const float4*)(b2 + c * 8 + 4);
        float v0 = r[0] * iv + bf2f((unsigned short)hr.x) + bA.x;
        float v1 = r[1] * iv + bf2f((unsigned short)(hr.x >> 16)) + bA.y;
        float v2 = r[2] * iv + bf2f((unsigned short)hr.y) + bA.z;
        float v3 = r[3] * iv + bf2f((unsigned short)(hr.y >> 16)) + bA.w;
        float v4 = r[4] * iv + bf2f((unsigned short)hr.z) + bB.x;
        float v5 = r[5] * iv + bf2f((unsigned short)(hr.z >> 16)) + bB.y;
        float v6 = r[6] * iv + bf2f((unsigned short)hr.w) + bB.z;
        float v7 = r[7] * iv + bf2f((unsigned short)(hr.w >> 16)) + bB.w;
        unsigned p0 = (unsigned)f2bf(v0) | ((unsigned)f2bf(v1) << 16);
        unsigned p1 = (unsigned)f2bf(v2) | ((unsigned)f2bf(v3) << 16);
        unsigned p2 = (unsigned)f2bf(v4) | ((unsigned)f2bf(v5) << 16);
        unsigned p3 = (unsigned)f2bf(v6) | ((unsigned)f2bf(v7) << 16);
        uint4 o; o.x = p0; o.y = p1; o.z = p2; o.w = p3;
        *(uint4*)(z + (size_t)node * 64 + c * 8) = o;
    }
}

// ---------------- fused double-GEMM ----------------
// Stage 1: T = relu(A @ Wp1 + bias1)  (A: n x K1 bf16, T: 64 x 256 tile in LDS)
// Stage 2: C = T @ Wp2 (+ bias2)      (C: n x (NBW2*64))
template <int K1, int NBW2, bool OUTBF>
__global__ __launch_bounds__(256) void gemm_fused(
    const unsigned short* __restrict__ A,
    const unsigned short* __restrict__ Bp1, const float* __restrict__ bias1,
    const unsigned short* __restrict__ Bp2, const float* __restrict__ bias2,
    void* __restrict__ Cv, int n)
{
    constexpr int KS1 = K1 / 32;
    constexpr int N2 = NBW2 * 64;
    constexpr int NB2 = NBW2 * 4;
    __shared__ unsigned short ht[64][264];

    const int m0 = blockIdx.x * 64;
    const int lane = threadIdx.x & 63;
    const int w = threadIdx.x >> 6;
    const int quad = lane >> 4;
    const int l16 = lane & 15;

    // ---- stage 1 ----
    {
        f32x4 acc[4][4] = {};
        const unsigned short* Arow = A + (size_t)(m0 + l16) * K1 + quad * 8;
        for (int s = 0; s < KS1; ++s) {
            bf16x8 a[4];
#pragma unroll
            for (int mb = 0; mb < 4; ++mb)
                a[mb] = *(const bf16x8*)(Arow + (size_t)mb * 16 * K1 + s * 32);
#pragma unroll
            for (int jn = 0; jn < 4; ++jn) {
                int j = w * 4 + jn;
                bf16x8 b = *(const bf16x8*)(Bp1 + ((size_t)(s * 16 + j) * 64 + lane) * 8);
#pragma unroll
                for (int mb = 0; mb < 4; ++mb)
                    acc[mb][jn] = __builtin_amdgcn_mfma_f32_16x16x32_bf16(a[mb], b, acc[mb][jn], 0, 0, 0);
            }
        }
#pragma unroll
        for (int jn = 0; jn < 4; ++jn) {
            int col = (w * 4 + jn) * 16 + l16;
            float bv = bias1[col];
#pragma unroll
            for (int mb = 0; mb < 4; ++mb)
#pragma unroll
                for (int r = 0; r < 4; ++r) {
                    int row = mb * 16 + quad * 4 + r;
                    ht[row][col] = f2bf(fmaxf(acc[mb][jn][r] + bv, 0.f));
                }
        }
    }
    __syncthreads();

    // ---- stage 2 ----
    {
        f32x4 acc[4][NBW2] = {};
        for (int s = 0; s < 8; ++s) {
            bf16x8 a[4];
#pragma unroll
            for (int mb = 0; mb < 4; ++mb)
                a[mb] = *(const bf16x8*)&ht[mb * 16 + l16][s * 32 + quad * 8];
#pragma unroll
            for (int jn = 0; jn < NBW2; ++jn) {
                int j = w * NBW2 + jn;
                bf16x8 b = *(const bf16x8*)(Bp2 + ((size_t)(s * NB2 + j) * 64 + lane) * 8);
#pragma unroll
                for (int mb = 0; mb < 4; ++mb)
                    acc[mb][jn] = __builtin_amdgcn_mfma_f32_16x16x32_bf16(a[mb], b, acc[mb][jn], 0, 0, 0);
            }
        }
#pragma unroll
        for (int jn = 0; jn < NBW2; ++jn) {
            int col = (w * NBW2 + jn) * 16 + l16;
            float bv = bias2 ? bias2[col] : 0.f;
#pragma unroll
            for (int mb = 0; mb < 4; ++mb)
#pragma unroll
                for (int r = 0; r < 4; ++r) {
                    int row = m0 + mb * 16 + quad * 4 + r;
                    if (row < n) {
                        float v = acc[mb][jn][r] + bv;
                        if (OUTBF)
                            ((unsigned short*)Cv)[(size_t)row * N2 + col] = f2bf(v);
                        else
                            ((float*)Cv)[(size_t)row * N2 + col] = v;
                    }
                }
        }
    }
}

extern "C" void kernel_launch(void* const* d_in, const int* in_sizes, int n_in,
                              void* d_out, int out_size, void* d_ws, size_t ws_size,
                              hipStream_t stream) {
    const float* x      = (const float*)d_in[0];
    const int*   ei     = (const int*)d_in[1];
    const float* W1g    = (const float*)d_in[2];   // (8,64,256): [0] = first 16384
    const float* root1  = (const float*)d_in[3];
    const float* b1     = (const float*)d_in[4];
    const float* W2g    = (const float*)d_in[5];   // (8,256,64): [0] = first 16384
    const float* root2  = (const float*)d_in[6];
    const float* b2     = (const float*)d_in[7];
    const float* dw1    = (const float*)d_in[8];
    const float* db1    = (const float*)d_in[9];
    const float* dw2    = (const float*)d_in[10];
    const float* db2    = (const float*)d_in[11];
    float* out = (float*)d_out;

    const int N = in_sizes[0] / 64;
    const int E = in_sizes[1] / 2;
    const int Npad = N + 64;
    const int* srcv = ei;
    const int* dstv = ei + E;

    char* ws = (char*)d_ws;
    auto alloc = [&](size_t bytes) -> void* {
        void* p = (void*)ws;
        ws += (bytes + 255) & ~(size_t)255;
        return p;
    };
    int*   bcnt   = (int*)alloc(1024);               // per-bucket counts (256)
    int*   bcur   = (int*)alloc(1024);               // 0-based bucket cursors
    int*   offs   = (int*)alloc((size_t)(N + 1) * 4);
    float* invd   = (float*)alloc((size_t)N * 4);
    int*   esrc   = (int*)alloc((size_t)E * 4);
    int*   epack  = (int*)alloc((size_t)E * 4);
    unsigned short* Pb1 = (unsigned short*)alloc(32768 * 2);
    unsigned short* Pb2 = (unsigned short*)alloc(32768 * 2);
    unsigned short* Pd1 = (unsigned short*)alloc(16384 * 2);
    unsigned short* Pd2 = (unsigned short*)alloc(16384 * 2);
    unsigned short* ab1    = (unsigned short*)alloc((size_t)Npad * 128 * 2);  // [agg1 | xb]
    unsigned short* hwroot = (unsigned short*)alloc((size_t)Npad * 128 * 2);
    unsigned short* z      = (unsigned short*)alloc((size_t)Npad * 64 * 2);

    hipMemsetAsync(bcnt, 0, 2048, stream);           // bcnt + bcur (adjacent)

    int gb = (N + 63) / 64;
    int nbkt = (N + 255) / 256;
    int pa = (E + 4095) / 4096;
    int pa2 = (E + 2047) / 2048;
    int pb_pack = (98304 + N * 16 + THREADS - 1) / THREADS;

    // packs + x->bf16 + bucket histogram (one kernel, disjoint block ranges)
    prep_kernel<<<pb_pack + pa, THREADS, 0, stream>>>(
        W1g, root1, W2g, root2, dw1, dw2, x, dstv, bcnt,
        Pb1, Pb2, Pd1, Pd2, ab1, N, E, pb_pack);
    // bucket-level CSR (bases computed locally from bcnt in each kernel)
    partition_edges<<<pa2, 512, 0, stream>>>(srcv, dstv, bcnt, bcur, epack, E);
    bucket_fill2<<<nbkt, 1024, 0, stream>>>(epack, bcnt, offs, invd, esrc, N);

    // layer 1 agg + fused [L1 GEMM -> L2 projection]
    agg_x4<<<(N + 3) / 4, THREADS, 0, stream>>>(ab1, esrc, offs, invd, N);
    gemm_fused<128, 2, true><<<gb, 256, 0, stream>>>(ab1, Pb1, b1, Pb2, nullptr, hwroot, N);
    // layer 2 gather + epilogue
    agg_z4<<<(N + 3) / 4, THREADS, 0, stream>>>(hwroot, esrc, offs, invd, b2, z, N);
    // fused decoder [dec1 -> dec2]
    gemm_fused<64, 1, false><<<gb, 256, 0, stream>>>(z, Pd1, db1, Pd2, db2, out, N);
}